// Round 5
// baseline (207.028 us; speedup 1.0000x reference)
//
#include <hip/hip_runtime.h>

#define BB 16
#define SS 2048
#define NTOK (BB*SS)
#define FF 512
#define EPSF 1e-5f

#if __has_builtin(__builtin_amdgcn_exp2f)
#define EXP2F(x) __builtin_amdgcn_exp2f(x)
#else
#define EXP2F(x) exp2f(x)
#endif

typedef float v2f __attribute__((ext_vector_type(2)));

// ---------------- ws float layout ----------------
// sm   : [L][64]        fused small mats (exp2-prescaled)  @ 0        (128)
// w1t  : [L][512][12]   {w1col[4], w2row[4], b1, pad3}     @ 128      (12288)
// X1   : [NTOK][4]                                         @ 12416    (131072)
// f0   : [NTOK][12]     AoS {P[4], VT[4], R, pad3}         @ 143488   (393216)
// f1   : [NTOK][12]                                        @ 536704   (393216)

__device__ __forceinline__ float wred64(float v) {
#pragma unroll
  for (int m = 32; m > 0; m >>= 1) v += __shfl_xor(v, m, 64);
  return v;
}

// lane-broadcast a float from lane l (uniform l) via v_readlane -> SGPR
__device__ __forceinline__ float rdl(float v, int l) {
  union { float f; int i; } u; u.f = v;
  u.i = __builtin_amdgcn_readlane(u.i, l);
  return u.f;
}

// sm layout (per layer, stride 64):
// 0:M4[16] (bw2*Wq^T Wk)   16:Bk[16] (-.5 bw2 Wk^T Wk)   32:WVO[16] (Wv*Wo)
// 48:ak[4]  52:bvo[4]  56:ck      where bw2 = bw^2 * log2(e)

__global__ __launch_bounds__(64) void prep_kernel(
    const float* __restrict__ Wq, const float* __restrict__ bq,
    const float* __restrict__ Wk, const float* __restrict__ bk,
    const float* __restrict__ Wv, const float* __restrict__ bv,
    const float* __restrict__ Wo, const float* __restrict__ bw,
    const float* __restrict__ W1, const float* __restrict__ b1,
    const float* __restrict__ W2,
    float* __restrict__ sm, float* __restrict__ w1t)
{
  const int i = blockIdx.x;       // layer
  const int lane = threadIdx.x;   // 0..63
  float m4[4][4] = {{0}}, gkk[4][4] = {{0}}, wvo[4][4] = {{0}};
  float akk[4] = {0}, bvo[4] = {0};
  float ck1 = 0.f, ck2 = 0.f;

  for (int h = lane; h < 256; h += 64) {
    float vq[4], vk[4], vv[4], wo4[4];
#pragma unroll
    for (int a = 0; a < 4; ++a) {
      vq[a]  = Wq[(i*4 + a)*256 + h];
      vk[a]  = Wk[(i*4 + a)*256 + h];
      vv[a]  = Wv[(i*4 + a)*256 + h];
      wo4[a] = Wo[(i*256 + h)*4 + a];
    }
    const float bqh = bq[i*256 + h], bkh = bk[i*256 + h], bvh = bv[i*256 + h];
#pragma unroll
    for (int a = 0; a < 4; ++a) {
#pragma unroll
      for (int c = 0; c < 4; ++c) {
        m4[a][c]  = fmaf(vq[a], vk[c], m4[a][c]);
        gkk[a][c] = fmaf(vk[a], vk[c], gkk[a][c]);
        wvo[a][c] = fmaf(vv[a], wo4[c], wvo[a][c]);
      }
      akk[a] = fmaf(vk[a], bqh - bkh, akk[a]);
      bvo[a] = fmaf(bvh, wo4[a], bvo[a]);
    }
    ck1 = fmaf(bqh, bkh, ck1);
    ck2 = fmaf(bkh, bkh, ck2);
  }
#pragma unroll
  for (int a = 0; a < 4; ++a) {
#pragma unroll
    for (int c = 0; c < 4; ++c) {
      m4[a][c]  = wred64(m4[a][c]);
      gkk[a][c] = wred64(gkk[a][c]);
      wvo[a][c] = wred64(wvo[a][c]);
    }
    akk[a] = wred64(akk[a]);
    bvo[a] = wred64(bvo[a]);
  }
  ck1 = wred64(ck1); ck2 = wred64(ck2);

  if (lane == 0) {
    const float bwv = bw[i];
    const float bw2 = bwv * bwv * 1.44269504088896f;   // exp2 prescale
    float* s = sm + i*64;
#pragma unroll
    for (int a = 0; a < 4; ++a) {
#pragma unroll
      for (int c = 0; c < 4; ++c) {
        s[a*4+c]      = bw2 * m4[a][c];
        s[16 + a*4+c] = -0.5f * bw2 * gkk[a][c];
        s[32 + a*4+c] = wvo[a][c];
      }
      s[48+a] = bw2 * akk[a];
      s[52+a] = bvo[a];
    }
    s[56] = bw2 * (ck1 - 0.5f * ck2);
  }
  // FFN weight repack: w1t[f] = {W1[:,f], W2[f,:], b1[f], pad}
  for (int f = lane; f < FF; f += 64) {
    float* rec = w1t + (i*FF + f)*12;
#pragma unroll
    for (int c = 0; c < 4; ++c) rec[c]   = W1[(i*4 + c)*FF + f];
#pragma unroll
    for (int c = 0; c < 4; ++c) rec[4+c] = W2[(i*FF + f)*4 + c];
    rec[8] = b1[i*FF + f];
    rec[9] = 0.f; rec[10] = 0.f; rec[11] = 0.f;
  }
}

// feat record: {P[4], VT[4], R}; query-side constant dropped (cancels in softmax)
__device__ __forceinline__ void compute_feat(const float x[4], const float* __restrict__ s,
                                             float* __restrict__ featrec)
{
  float P[4], VT[4], tk[4];
#pragma unroll
  for (int a = 0; a < 4; ++a) {
    P[a]  = fmaf(s[a*4+3], x[3], fmaf(s[a*4+2], x[2], fmaf(s[a*4+1], x[1], s[a*4+0]*x[0])));
    tk[a] = fmaf(s[16+a*4+3], x[3], fmaf(s[16+a*4+2], x[2], fmaf(s[16+a*4+1], x[1], s[16+a*4+0]*x[0])));
    VT[a] = s[52+a] + fmaf(s[32+3*4+a], x[3], fmaf(s[32+2*4+a], x[2], fmaf(s[32+1*4+a], x[1], s[32+0*4+a]*x[0])));
  }
  float R = s[56];
#pragma unroll
  for (int a = 0; a < 4; ++a) R = fmaf(tk[a] + s[48+a], x[a], R);
  float4* fp = (float4*)featrec;
  fp[0] = make_float4(P[0], P[1], P[2], P[3]);
  fp[1] = make_float4(VT[0], VT[1], VT[2], VT[3]);
  fp[2] = make_float4(R, 0.f, 0.f, 0.f);
}

// layer-0 key-feature records (AoS, 48B stride), straight from KEY/VALUE
__global__ __launch_bounds__(256) void feat_kernel(
    const float* __restrict__ KEY, const float* __restrict__ VALUE,
    const float* __restrict__ sm, float* __restrict__ feat)
{
  const int gq = blockIdx.x*256 + threadIdx.x;
  float xr[4] = {KEY[gq*3], KEY[gq*3+1], KEY[gq*3+2], VALUE[gq]};
  float fr[12];
  compute_feat(xr, sm, fr);
  float4* fp = (float4*)(feat + (size_t)gq*12);
  fp[0] = ((float4*)fr)[0];
  fp[1] = ((float4*)fr)[1];
  fp[2] = ((float4*)fr)[2];
}

__device__ __forceinline__ void ln4(const float t[4], const float* __restrict__ g,
                                    const float* __restrict__ b, float r[4])
{
  const float m = 0.25f*(t[0]+t[1]+t[2]+t[3]);
  const float d0 = t[0]-m, d1 = t[1]-m, d2 = t[2]-m, d3 = t[3]-m;
  const float v = 0.25f*(d0*d0 + d1*d1 + d2*d2 + d3*d3);
  const float sc = rsqrtf(v + EPSF);
  r[0] = fmaf(d0*sc, g[0], b[0]);
  r[1] = fmaf(d1*sc, g[1], b[1]);
  r[2] = fmaf(d2*sc, g[2], b[2]);
  r[3] = fmaf(d3*sc, g[3], b[3]);
}

// Fused per-layer kernel: block = 1024 thr (16 waves), 128 queries x all 2048 keys.
// Wave wv streams keys [kbase + wv*128, +128): lane i holds record i of each
// 64-record batch in VGPRs (one coalesced load), per-key broadcast via
// v_readlane -> SGPR. Inner loop: pure VALU, no LDS, no VMEM, no barriers.
// 2 queries/lane pk-packed (lane l -> queries qbase+l, qbase+64+l).
// Epilogue: 16-wave LDS reduce, softmax-normalize, +residual, LN1,
// FFN (8 fc x 64 f), LN2, outputs.
__global__ __launch_bounds__(1024, 4) void layer_kernel(
    const float* __restrict__ KEY, const float* __restrict__ VALUE,
    const float* __restrict__ X, const float* __restrict__ feat,
    const float* __restrict__ w1t, const float* __restrict__ smn,
    const float* __restrict__ bo, const float* __restrict__ g1, const float* __restrict__ be1,
    const float* __restrict__ b2v, const float* __restrict__ g2, const float* __restrict__ be2,
    float* __restrict__ Xout, float* __restrict__ featout,
    const float* __restrict__ Wfc, const float* __restrict__ bfc,
    float* __restrict__ outp, int first, int last)
{
  const int bid = blockIdx.x;                  // 256 blocks
  const int b = bid >> 4, qg = bid & 15;
  const int qbase = (b << 11) + (qg << 7);     // 128 queries
  const int kbase = b << 11;
  const int tid = threadIdx.x;
  const int lane = tid & 63;
  const int wv = __builtin_amdgcn_readfirstlane(tid >> 6);   // 0..15, SGPR-uniform

  __shared__ float smem[12288 + 512];
  float* red  = smem;           // [16][64][12] partials
  float* ress = smem + 12288;   // [128][4]
  float* redf = smem;           // [8][128][4] aliases red (dead after reduce barrier)

  // this wave's two 64-record key batches -> registers (coalesced, lane i = record i)
  const float* fr0 = feat + (size_t)(kbase + (wv << 7) + lane) * 12;
  const float4 rP0 = *(const float4*)fr0;
  const float4 rV0 = *(const float4*)(fr0 + 4);
  const float  rR0 = fr0[8];
  const float* fr1 = fr0 + 64*12;
  const float4 rP1 = *(const float4*)fr1;
  const float4 rV1 = *(const float4*)(fr1 + 4);
  const float  rR1 = fr1[8];

  // 2 queries per lane, component-packed for v_pk_fma_f32
  v2f xq0, xq1, xq2, xq3;
  if (first) {
    const int qa = qbase + lane, qb = qa + 64;
    xq0 = v2f{KEY[qa*3    ], KEY[qb*3    ]};
    xq1 = v2f{KEY[qa*3 + 1], KEY[qb*3 + 1]};
    xq2 = v2f{KEY[qa*3 + 2], KEY[qb*3 + 2]};
    xq3 = v2f{VALUE[qa], VALUE[qb]};
  } else {
    const float4 xa = *(const float4*)(X + (size_t)(qbase + lane     )*4);
    const float4 xb = *(const float4*)(X + (size_t)(qbase + 64 + lane)*4);
    xq0 = v2f{xa.x, xb.x}; xq1 = v2f{xa.y, xb.y};
    xq2 = v2f{xa.z, xb.z}; xq3 = v2f{xa.w, xb.w};
  }

  v2f aaxy = v2f{0.f,0.f}, aazw = v2f{0.f,0.f};   // query qbase+lane
  v2f abxy = v2f{0.f,0.f}, abzw = v2f{0.f,0.f};   // query qbase+64+lane
  v2f ad   = v2f{0.f,0.f};

  // batch 0
#pragma unroll 4
  for (int k = 0; k < 64; ++k) {
    const float P0 = rdl(rP0.x, k), P1 = rdl(rP0.y, k);
    const float P2 = rdl(rP0.z, k), P3 = rdl(rP0.w, k);
    const float V0 = rdl(rV0.x, k), V1 = rdl(rV0.y, k);
    const float V2 = rdl(rV0.z, k), V3 = rdl(rV0.w, k);
    const float Rk = rdl(rR0, k);
    v2f l = __builtin_elementwise_fma(xq0, v2f{P0, P0}, v2f{Rk, Rk});
    l = __builtin_elementwise_fma(xq1, v2f{P1, P1}, l);
    l = __builtin_elementwise_fma(xq2, v2f{P2, P2}, l);
    l = __builtin_elementwise_fma(xq3, v2f{P3, P3}, l);
    const float e0 = EXP2F(l.x);
    const float e1 = EXP2F(l.y);
    const v2f Vxy = v2f{V0, V1}, Vzw = v2f{V2, V3};
    const v2f e0v = v2f{e0, e0}, e1v = v2f{e1, e1};
    aaxy = __builtin_elementwise_fma(e0v, Vxy, aaxy);
    aazw = __builtin_elementwise_fma(e0v, Vzw, aazw);
    abxy = __builtin_elementwise_fma(e1v, Vxy, abxy);
    abzw = __builtin_elementwise_fma(e1v, Vzw, abzw);
    ad += v2f{e0, e1};
  }
  // batch 1
#pragma unroll 4
  for (int k = 0; k < 64; ++k) {
    const float P0 = rdl(rP1.x, k), P1 = rdl(rP1.y, k);
    const float P2 = rdl(rP1.z, k), P3 = rdl(rP1.w, k);
    const float V0 = rdl(rV1.x, k), V1 = rdl(rV1.y, k);
    const float V2 = rdl(rV1.z, k), V3 = rdl(rV1.w, k);
    const float Rk = rdl(rR1, k);
    v2f l = __builtin_elementwise_fma(xq0, v2f{P0, P0}, v2f{Rk, Rk});
    l = __builtin_elementwise_fma(xq1, v2f{P1, P1}, l);
    l = __builtin_elementwise_fma(xq2, v2f{P2, P2}, l);
    l = __builtin_elementwise_fma(xq3, v2f{P3, P3}, l);
    const float e0 = EXP2F(l.x);
    const float e1 = EXP2F(l.y);
    const v2f Vxy = v2f{V0, V1}, Vzw = v2f{V2, V3};
    const v2f e0v = v2f{e0, e0}, e1v = v2f{e1, e1};
    aaxy = __builtin_elementwise_fma(e0v, Vxy, aaxy);
    aazw = __builtin_elementwise_fma(e0v, Vzw, aazw);
    abxy = __builtin_elementwise_fma(e1v, Vxy, abxy);
    abzw = __builtin_elementwise_fma(e1v, Vzw, abzw);
    ad += v2f{e0, e1};
  }

  // per-wave partials -> LDS
  {
    float* rr = red + (size_t)((wv << 6) + lane)*12;
    *(float4*)rr       = make_float4(aaxy.x, aaxy.y, aazw.x, aazw.y);
    *(float4*)(rr + 4) = make_float4(abxy.x, abxy.y, abzw.x, abzw.y);
    rr[8] = ad.x; rr[9] = ad.y;
  }
  __syncthreads();

  // 16-wave reduce + softmax normalize + residual + LN1 (query qbase+tid for tid<128)
  if (tid < 128) {
    const int ql = tid & 63, sel = tid >> 6;
    float s0 = 0.f, s1 = 0.f, s2 = 0.f, s3 = 0.f, sd = 0.f;
#pragma unroll
    for (int w = 0; w < 16; ++w) {
      const float* rr = red + (size_t)((w << 6) + ql)*12;
      const float4 vv = *(const float4*)(rr + sel*4);
      s0 += vv.x; s1 += vv.y; s2 += vv.z; s3 += vv.w;
      sd += rr[8 + sel];
    }
    const float inv = 1.0f / sd;
    const int gq = qbase + tid;
    float xv0, xv1, xv2, xv3;
    if (first) {
      xv0 = KEY[gq*3]; xv1 = KEY[gq*3+1]; xv2 = KEY[gq*3+2]; xv3 = VALUE[gq];
    } else {
      const float4 xv = *(const float4*)(X + (size_t)gq*4);
      xv0 = xv.x; xv1 = xv.y; xv2 = xv.z; xv3 = xv.w;
    }
    float t4[4];
    t4[0] = xv0 + fmaf(s0, inv, bo[0]);
    t4[1] = xv1 + fmaf(s1, inv, bo[1]);
    t4[2] = xv2 + fmaf(s2, inv, bo[2]);
    t4[3] = xv3 + fmaf(s3, inv, bo[3]);
    float r[4];
    ln4(t4, g1, be1, r);
    *(float4*)(ress + tid*4) = make_float4(r[0], r[1], r[2], r[3]);
  }
  __syncthreads();

  // FFN: tok = tid&127, fc = tid>>7 (8 chunks of 64 f); redf aliases dead red region
  const int tok = tid & 127, fc = tid >> 7;
  const float4 rv = *(const float4*)(ress + tok*4);
  float fa0 = 0.f, fa1 = 0.f, fa2 = 0.f, fa3 = 0.f;
  const float* wt = w1t + (size_t)fc*64*12;
#pragma unroll 4
  for (int f = 0; f < 64; ++f) {
    const float* rec = wt + f*12;
    const float4 w1r = *(const float4*)rec;
    const float4 w2r = *(const float4*)(rec + 4);
    const float b1f = rec[8];
    float h = fmaf(rv.w, w1r.w, fmaf(rv.z, w1r.z, fmaf(rv.y, w1r.y, fmaf(rv.x, w1r.x, b1f))));
    h = fmaxf(h, 0.f);
    fa0 = fmaf(h, w2r.x, fa0);
    fa1 = fmaf(h, w2r.y, fa1);
    fa2 = fmaf(h, w2r.z, fa2);
    fa3 = fmaf(h, w2r.w, fa3);
  }
  *(float4*)(redf + (size_t)((fc << 7) + tok)*4) = make_float4(fa0, fa1, fa2, fa3);
  __syncthreads();

  // FFN reduce + residual + LN2 + output (X + next-layer feats, or final fc)
  if (tid < 128) {
    float t2[4];
#pragma unroll
    for (int c = 0; c < 4; ++c) {
      float s = b2v[c];
#pragma unroll
      for (int k = 0; k < 8; ++k) s += redf[(size_t)((k << 7) + tid)*4 + c];
      t2[c] = ress[tid*4 + c] + s;
    }
    float y[4];
    ln4(t2, g2, be2, y);
    const int gq = qbase + tid;
    if (last) {
      outp[gq] = fmaf(y[3], Wfc[3], fmaf(y[2], Wfc[2], fmaf(y[1], Wfc[1], fmaf(y[0], Wfc[0], bfc[0]))));
    } else {
      *(float4*)(Xout + (size_t)gq*4) = make_float4(y[0], y[1], y[2], y[3]);
      float fr[12];
      compute_feat(y, smn, fr);
      float4* fp = (float4*)(featout + (size_t)gq*12);
      fp[0] = ((float4*)fr)[0];
      fp[1] = ((float4*)fr)[1];
      fp[2] = ((float4*)fr)[2];
    }
  }
}

extern "C" void kernel_launch(void* const* d_in, const int* in_sizes, int n_in,
                              void* d_out, int out_size, void* d_ws, size_t ws_size,
                              hipStream_t stream)
{
  const float* KEY   = (const float*)d_in[0];
  const float* VALUE = (const float*)d_in[1];
  const float* Wq  = (const float*)d_in[2];
  const float* bq  = (const float*)d_in[3];
  const float* Wk  = (const float*)d_in[4];
  const float* bk  = (const float*)d_in[5];
  const float* Wv  = (const float*)d_in[6];
  const float* bv  = (const float*)d_in[7];
  const float* Wo  = (const float*)d_in[8];
  const float* bo  = (const float*)d_in[9];
  const float* bw  = (const float*)d_in[10];
  const float* g1  = (const float*)d_in[11];
  const float* be1 = (const float*)d_in[12];
  const float* W1  = (const float*)d_in[13];
  const float* b1  = (const float*)d_in[14];
  const float* W2  = (const float*)d_in[15];
  const float* b2  = (const float*)d_in[16];
  const float* g2  = (const float*)d_in[17];
  const float* be2 = (const float*)d_in[18];
  const float* Wfc = (const float*)d_in[19];
  const float* bfc = (const float*)d_in[20];
  float* out = (float*)d_out;

  float* w    = (float*)d_ws;
  float* sm   = w;              // 128
  float* w1t  = w + 128;        // 12288
  float* X1   = w + 12416;      // 131072
  float* f0   = w + 143488;     // 393216 (16B-aligned records)
  float* f1   = w + 536704;     // 393216

  prep_kernel<<<2, 64, 0, stream>>>(Wq, bq, Wk, bk, Wv, bv, Wo, bw,
                                    W1, b1, W2, sm, w1t);
  feat_kernel<<<128, 256, 0, stream>>>(KEY, VALUE, sm, f0);

  // layer 0: queries/residual from KEY/VALUE, keys from f0; writes X1 + f1 (layer-1 sm)
  layer_kernel<<<256, 1024, 0, stream>>>(KEY, VALUE, X1, f0,
      w1t, sm + 64,
      bo, g1, be1, b2, g2, be2,
      X1, f1, Wfc, bfc, out, 1, 0);

  // layer 1: consumes X1/f1, produces final output
  layer_kernel<<<256, 1024, 0, stream>>>(KEY, VALUE, X1, f1,
      w1t + FF*12, sm,
      bo + 4, g1 + 4, be1 + 4, b2 + 4, g2 + 4, be2 + 4,
      X1, f1, Wfc, bfc, out, 0, 1);
}

// Round 6
// 183.079 us; speedup vs baseline: 1.1308x; 1.1308x over previous
//
#include <hip/hip_runtime.h>

#define BB 16
#define SS 2048
#define NTOK (BB*SS)
#define NPAIR (NTOK/2)
#define PLANE (NPAIR*4)
#define FF 512
#define EPSF 1e-5f

#if __has_builtin(__builtin_amdgcn_exp2f)
#define EXP2F(x) __builtin_amdgcn_exp2f(x)
#else
#define EXP2F(x) exp2f(x)
#endif

typedef float v2f __attribute__((ext_vector_type(2)));

// ---------------- ws float layout ----------------
// sm   : [L][64]        fused small mats (exp2-prescaled)  @ 0        (128)
// w1t  : [L][512][12]   {w1col[4], w2row[4], b1, pad3}     @ 128      (12288)
// X1   : [NTOK][4]                                         @ 12416    (131072)
// f0   : [5][NPAIR][4]  pair-interleaved SoA planes        @ 143488   (327680)
//        plane pl, pair p: {c(2p),c(2p+1),c'(2p),c'(2p+1)} c=2pl, c'=2pl+1
//        plane 4: {R(2p), R(2p+1), 0, 0}
// f1   : same                                              @ 471168   (327680)

__device__ __forceinline__ float wred64(float v) {
#pragma unroll
  for (int m = 32; m > 0; m >>= 1) v += __shfl_xor(v, m, 64);
  return v;
}

__device__ __forceinline__ float rflf(float v) {
  union { float f; int i; } u; u.f = v;
  u.i = __builtin_amdgcn_readfirstlane(u.i);
  return u.f;
}

// sm layout (per layer, stride 64):
// 0:M4[16] (bw2*Wq^T Wk)   16:Bk[16] (-.5 bw2 Wk^T Wk)   32:WVO[16] (Wv*Wo)
// 48:ak[4]  52:bvo[4]  56:ck      where bw2 = bw^2 * log2(e)

__global__ __launch_bounds__(64) void prep_kernel(
    const float* __restrict__ Wq, const float* __restrict__ bq,
    const float* __restrict__ Wk, const float* __restrict__ bk,
    const float* __restrict__ Wv, const float* __restrict__ bv,
    const float* __restrict__ Wo, const float* __restrict__ bw,
    const float* __restrict__ W1, const float* __restrict__ b1,
    const float* __restrict__ W2,
    float* __restrict__ sm, float* __restrict__ w1t)
{
  const int i = blockIdx.x;       // layer
  const int lane = threadIdx.x;   // 0..63
  float m4[4][4] = {{0}}, gkk[4][4] = {{0}}, wvo[4][4] = {{0}};
  float akk[4] = {0}, bvo[4] = {0};
  float ck1 = 0.f, ck2 = 0.f;

  for (int h = lane; h < 256; h += 64) {
    float vq[4], vk[4], vv[4], wo4[4];
#pragma unroll
    for (int a = 0; a < 4; ++a) {
      vq[a]  = Wq[(i*4 + a)*256 + h];
      vk[a]  = Wk[(i*4 + a)*256 + h];
      vv[a]  = Wv[(i*4 + a)*256 + h];
      wo4[a] = Wo[(i*256 + h)*4 + a];
    }
    const float bqh = bq[i*256 + h], bkh = bk[i*256 + h], bvh = bv[i*256 + h];
#pragma unroll
    for (int a = 0; a < 4; ++a) {
#pragma unroll
      for (int c = 0; c < 4; ++c) {
        m4[a][c]  = fmaf(vq[a], vk[c], m4[a][c]);
        gkk[a][c] = fmaf(vk[a], vk[c], gkk[a][c]);
        wvo[a][c] = fmaf(vv[a], wo4[c], wvo[a][c]);
      }
      akk[a] = fmaf(vk[a], bqh - bkh, akk[a]);
      bvo[a] = fmaf(bvh, wo4[a], bvo[a]);
    }
    ck1 = fmaf(bqh, bkh, ck1);
    ck2 = fmaf(bkh, bkh, ck2);
  }
#pragma unroll
  for (int a = 0; a < 4; ++a) {
#pragma unroll
    for (int c = 0; c < 4; ++c) {
      m4[a][c]  = wred64(m4[a][c]);
      gkk[a][c] = wred64(gkk[a][c]);
      wvo[a][c] = wred64(wvo[a][c]);
    }
    akk[a] = wred64(akk[a]);
    bvo[a] = wred64(bvo[a]);
  }
  ck1 = wred64(ck1); ck2 = wred64(ck2);

  if (lane == 0) {
    const float bwv = bw[i];
    const float bw2 = bwv * bwv * 1.44269504088896f;   // exp2 prescale
    float* s = sm + i*64;
#pragma unroll
    for (int a = 0; a < 4; ++a) {
#pragma unroll
      for (int c = 0; c < 4; ++c) {
        s[a*4+c]      = bw2 * m4[a][c];
        s[16 + a*4+c] = -0.5f * bw2 * gkk[a][c];
        s[32 + a*4+c] = wvo[a][c];
      }
      s[48+a] = bw2 * akk[a];
      s[52+a] = bvo[a];
    }
    s[56] = bw2 * (ck1 - 0.5f * ck2);
  }
  // FFN weight repack: w1t[f] = {W1[:,f], W2[f,:], b1[f], pad}
  for (int f = lane; f < FF; f += 64) {
    float* rec = w1t + (i*FF + f)*12;
#pragma unroll
    for (int c = 0; c < 4; ++c) rec[c]   = W1[(i*4 + c)*FF + f];
#pragma unroll
    for (int c = 0; c < 4; ++c) rec[4+c] = W2[(i*FF + f)*4 + c];
    rec[8] = b1[i*FF + f];
    rec[9] = 0.f; rec[10] = 0.f; rec[11] = 0.f;
  }
}

// feat record: {P[4], VT[4], R}; query-side constant dropped (cancels in softmax)
__device__ __forceinline__ void compute_feat(const float x[4], const float* __restrict__ s,
                                             float* __restrict__ featrec)
{
  float P[4], VT[4], tk[4];
#pragma unroll
  for (int a = 0; a < 4; ++a) {
    P[a]  = fmaf(s[a*4+3], x[3], fmaf(s[a*4+2], x[2], fmaf(s[a*4+1], x[1], s[a*4+0]*x[0])));
    tk[a] = fmaf(s[16+a*4+3], x[3], fmaf(s[16+a*4+2], x[2], fmaf(s[16+a*4+1], x[1], s[16+a*4+0]*x[0])));
    VT[a] = s[52+a] + fmaf(s[32+3*4+a], x[3], fmaf(s[32+2*4+a], x[2], fmaf(s[32+1*4+a], x[1], s[32+0*4+a]*x[0])));
  }
  float R = s[56];
#pragma unroll
  for (int a = 0; a < 4; ++a) R = fmaf(tk[a] + s[48+a], x[a], R);
  featrec[0]=P[0]; featrec[1]=P[1]; featrec[2]=P[2]; featrec[3]=P[3];
  featrec[4]=VT[0]; featrec[5]=VT[1]; featrec[6]=VT[2]; featrec[7]=VT[3];
  featrec[8]=R;
}

// layer-0 key features -> pair-interleaved SoA planes. thread = pair (2 tokens).
__global__ __launch_bounds__(256) void feat_kernel(
    const float* __restrict__ KEY, const float* __restrict__ VALUE,
    const float* __restrict__ sm, float* __restrict__ feat)
{
  const int p = blockIdx.x*256 + threadIdx.x;       // pair index
  const int ta = 2*p, tb = 2*p + 1;
  float xa[4] = {KEY[ta*3], KEY[ta*3+1], KEY[ta*3+2], VALUE[ta]};
  float xb[4] = {KEY[tb*3], KEY[tb*3+1], KEY[tb*3+2], VALUE[tb]};
  float fa[9], fb[9];
  compute_feat(xa, sm, fa);
  compute_feat(xb, sm, fb);
#pragma unroll
  for (int pl = 0; pl < 4; ++pl) {
    *(float4*)(feat + (size_t)pl*PLANE + (size_t)p*4) =
        make_float4(fa[2*pl], fb[2*pl], fa[2*pl+1], fb[2*pl+1]);
  }
  *(float4*)(feat + (size_t)4*PLANE + (size_t)p*4) =
      make_float4(fa[8], fb[8], 0.f, 0.f);
}

__device__ __forceinline__ void ln4(const float t[4], const float* __restrict__ g,
                                    const float* __restrict__ b, float r[4])
{
  const float m = 0.25f*(t[0]+t[1]+t[2]+t[3]);
  const float d0 = t[0]-m, d1 = t[1]-m, d2 = t[2]-m, d3 = t[3]-m;
  const float v = 0.25f*(d0*d0 + d1*d1 + d2*d2 + d3*d3);
  const float sc = rsqrtf(v + EPSF);
  r[0] = fmaf(d0*sc, g[0], b[0]);
  r[1] = fmaf(d1*sc, g[1], b[1]);
  r[2] = fmaf(d2*sc, g[2], b[2]);
  r[3] = fmaf(d3*sc, g[3], b[3]);
}

// Flipped-dataflow fused layer kernel: block = 512 thr (8 waves), 64 queries.
// Wave wv owns 8 queries (x in SGPRs via readfirstlane) and streams ALL 2048 keys
// of its batch, 2 keys/lane packed in v2f from pair-interleaved SoA planes
// (coalesced float4 loads; zero LDS, zero broadcast, zero barriers in main loop).
// acc[8q][5] v2f per lane; epilogue: horizontal add + 40x shfl_xor butterfly
// (queries wave-exclusive), then LN1 / FFN / LN2 as before.
__global__ __launch_bounds__(512, 4) void layer_kernel(
    const float* __restrict__ KEY, const float* __restrict__ VALUE,
    const float* __restrict__ X, const float* __restrict__ feat,
    const float* __restrict__ w1t, const float* __restrict__ smn,
    const float* __restrict__ bo, const float* __restrict__ g1, const float* __restrict__ be1,
    const float* __restrict__ b2v, const float* __restrict__ g2, const float* __restrict__ be2,
    float* __restrict__ Xout, float* __restrict__ featout,
    const float* __restrict__ Wfc, const float* __restrict__ bfc,
    float* __restrict__ outp, int first, int last)
{
  const int bid = blockIdx.x;                  // 512 blocks
  const int b = bid >> 5, qg = bid & 31;
  const int qbase = (b << 11) + (qg << 6);     // 64 queries per block
  const int tid = threadIdx.x;
  const int lane = tid & 63, wv = tid >> 6;    // wave 0..7
  const int q0 = qbase + wv*8;                 // this wave's 8 queries

  __shared__ float sums[8*8*9];    // [wave][q][9] (stride 9: bank-friendly)
  __shared__ float ress[64*4];
  __shared__ float redf[8*64*4];

  // 8 queries -> SGPRs (uniform loads + readfirstlane)
  float qx0[8], qx1[8], qx2[8], qx3[8];
#pragma unroll
  for (int q = 0; q < 8; ++q) {
    const int gq = q0 + q;
    float a, bq_, c, d;
    if (first) {
      a = KEY[gq*3]; bq_ = KEY[gq*3+1]; c = KEY[gq*3+2]; d = VALUE[gq];
    } else {
      const float4 xv = *(const float4*)(X + (size_t)gq*4);
      a = xv.x; bq_ = xv.y; c = xv.z; d = xv.w;
    }
    qx0[q] = rflf(a); qx1[q] = rflf(bq_); qx2[q] = rflf(c); qx3[q] = rflf(d);
  }

  v2f aV0[8], aV1[8], aV2[8], aV3[8], aD[8];
#pragma unroll
  for (int q = 0; q < 8; ++q) {
    aV0[q] = v2f{0.f,0.f}; aV1[q] = v2f{0.f,0.f};
    aV2[q] = v2f{0.f,0.f}; aV3[q] = v2f{0.f,0.f};
    aD[q]  = v2f{0.f,0.f};
  }

  // key stream: 16 iters x 128 keys (2 packed keys per lane)
  const int pb = (b << 10) + lane;             // batch pair base + lane
#pragma unroll 2
  for (int it = 0; it < 16; ++it) {
    const size_t p4 = (size_t)(pb + (it << 6)) * 4;
    const float4 A = *(const float4*)(feat + p4);                     // P0a,P0b,P1a,P1b
    const float4 Bf = *(const float4*)(feat + (size_t)PLANE + p4);    // P2a,P2b,P3a,P3b
    const float4 C = *(const float4*)(feat + (size_t)2*PLANE + p4);   // V0a,V0b,V1a,V1b
    const float4 D = *(const float4*)(feat + (size_t)3*PLANE + p4);   // V2a,V2b,V3a,V3b
    const float4 E = *(const float4*)(feat + (size_t)4*PLANE + p4);   // Ra,Rb,-,-
    const v2f P0 = v2f{A.x, A.y},  P1 = v2f{A.z, A.w};
    const v2f P2 = v2f{Bf.x, Bf.y}, P3 = v2f{Bf.z, Bf.w};
    const v2f V0 = v2f{C.x, C.y},  V1 = v2f{C.z, C.w};
    const v2f V2 = v2f{D.x, D.y},  V3 = v2f{D.z, D.w};
    const v2f Rp = v2f{E.x, E.y};
#pragma unroll
    for (int q = 0; q < 8; ++q) {
      v2f l = __builtin_elementwise_fma(P0, v2f{qx0[q], qx0[q]}, Rp);
      l = __builtin_elementwise_fma(P1, v2f{qx1[q], qx1[q]}, l);
      l = __builtin_elementwise_fma(P2, v2f{qx2[q], qx2[q]}, l);
      l = __builtin_elementwise_fma(P3, v2f{qx3[q], qx3[q]}, l);
      const v2f e = v2f{EXP2F(l.x), EXP2F(l.y)};
      aV0[q] = __builtin_elementwise_fma(e, V0, aV0[q]);
      aV1[q] = __builtin_elementwise_fma(e, V1, aV1[q]);
      aV2[q] = __builtin_elementwise_fma(e, V2, aV2[q]);
      aV3[q] = __builtin_elementwise_fma(e, V3, aV3[q]);
      aD[q] += e;
    }
  }

  // horizontal (2 key-halves) + full-wave butterfly; all lanes end with the sums
  float s[8][5];
#pragma unroll
  for (int q = 0; q < 8; ++q) {
    s[q][0] = aV0[q].x + aV0[q].y;
    s[q][1] = aV1[q].x + aV1[q].y;
    s[q][2] = aV2[q].x + aV2[q].y;
    s[q][3] = aV3[q].x + aV3[q].y;
    s[q][4] = aD[q].x + aD[q].y;
  }
#pragma unroll
  for (int q = 0; q < 8; ++q)
#pragma unroll
    for (int c = 0; c < 5; ++c) s[q][c] = wred64(s[q][c]);

  if (lane == 0) {
    float* dst = sums + wv*72;
#pragma unroll
    for (int q = 0; q < 8; ++q) {
#pragma unroll
      for (int c = 0; c < 5; ++c) dst[q*9 + c] = s[q][c];
    }
  }
  __syncthreads();

  // softmax normalize + residual + LN1 (token t = tid for tid<64)
  if (tid < 64) {
    const float* sv = sums + tid*9;
    const float inv = 1.0f / sv[4];
    const int gq = qbase + tid;
    float xv0, xv1, xv2, xv3;
    if (first) {
      xv0 = KEY[gq*3]; xv1 = KEY[gq*3+1]; xv2 = KEY[gq*3+2]; xv3 = VALUE[gq];
    } else {
      const float4 xv = *(const float4*)(X + (size_t)gq*4);
      xv0 = xv.x; xv1 = xv.y; xv2 = xv.z; xv3 = xv.w;
    }
    float t4[4];
    t4[0] = xv0 + fmaf(sv[0], inv, bo[0]);
    t4[1] = xv1 + fmaf(sv[1], inv, bo[1]);
    t4[2] = xv2 + fmaf(sv[2], inv, bo[2]);
    t4[3] = xv3 + fmaf(sv[3], inv, bo[3]);
    float r[4];
    ln4(t4, g1, be1, r);
    *(float4*)(ress + tid*4) = make_float4(r[0], r[1], r[2], r[3]);
  }
  __syncthreads();

  // FFN: fc = wave (8 chunks of 64 f), tok = lane
  const int tok = lane, fc = wv;
  const float4 rv = *(const float4*)(ress + tok*4);
  float fa0 = 0.f, fa1 = 0.f, fa2 = 0.f, fa3 = 0.f;
  const float* wt = w1t + (size_t)fc*64*12;
#pragma unroll 4
  for (int f = 0; f < 64; ++f) {
    const float* rec = wt + f*12;
    const float4 w1r = *(const float4*)rec;
    const float4 w2r = *(const float4*)(rec + 4);
    const float b1f = rec[8];
    float h = fmaf(rv.w, w1r.w, fmaf(rv.z, w1r.z, fmaf(rv.y, w1r.y, fmaf(rv.x, w1r.x, b1f))));
    h = fmaxf(h, 0.f);
    fa0 = fmaf(h, w2r.x, fa0);
    fa1 = fmaf(h, w2r.y, fa1);
    fa2 = fmaf(h, w2r.z, fa2);
    fa3 = fmaf(h, w2r.w, fa3);
  }
  *(float4*)(redf + (size_t)((fc << 6) + tok)*4) = make_float4(fa0, fa1, fa2, fa3);
  __syncthreads();

  // FFN reduce + residual + LN2 + output (X + next-layer feat planes, or final fc)
  if (tid < 64) {
    float t2[4];
#pragma unroll
    for (int c = 0; c < 4; ++c) {
      float sa = b2v[c];
#pragma unroll
      for (int k = 0; k < 8; ++k) sa += redf[(size_t)((k << 6) + tid)*4 + c];
      t2[c] = ress[tid*4 + c] + sa;
    }
    float y[4];
    ln4(t2, g2, be2, y);
    const int gq = qbase + tid;
    if (last) {
      outp[gq] = fmaf(y[3], Wfc[3], fmaf(y[2], Wfc[2], fmaf(y[1], Wfc[1], fmaf(y[0], Wfc[0], bfc[0]))));
    } else {
      *(float4*)(Xout + (size_t)gq*4) = make_float4(y[0], y[1], y[2], y[3]);
      float fr[9];
      compute_feat(y, smn, fr);
      const int p = gq >> 1, par = gq & 1;
#pragma unroll
      for (int c = 0; c < 8; ++c)
        featout[(size_t)(c >> 1)*PLANE + (size_t)p*4 + (c & 1)*2 + par] = fr[c];
      featout[(size_t)4*PLANE + (size_t)p*4 + par] = fr[8];
    }
  }
}

extern "C" void kernel_launch(void* const* d_in, const int* in_sizes, int n_in,
                              void* d_out, int out_size, void* d_ws, size_t ws_size,
                              hipStream_t stream)
{
  const float* KEY   = (const float*)d_in[0];
  const float* VALUE = (const float*)d_in[1];
  const float* Wq  = (const float*)d_in[2];
  const float* bq  = (const float*)d_in[3];
  const float* Wk  = (const float*)d_in[4];
  const float* bk  = (const float*)d_in[5];
  const float* Wv  = (const float*)d_in[6];
  const float* bv  = (const float*)d_in[7];
  const float* Wo  = (const float*)d_in[8];
  const float* bo  = (const float*)d_in[9];
  const float* bw  = (const float*)d_in[10];
  const float* g1  = (const float*)d_in[11];
  const float* be1 = (const float*)d_in[12];
  const float* W1  = (const float*)d_in[13];
  const float* b1  = (const float*)d_in[14];
  const float* W2  = (const float*)d_in[15];
  const float* b2  = (const float*)d_in[16];
  const float* g2  = (const float*)d_in[17];
  const float* be2 = (const float*)d_in[18];
  const float* Wfc = (const float*)d_in[19];
  const float* bfc = (const float*)d_in[20];
  float* out = (float*)d_out;

  float* w    = (float*)d_ws;
  float* sm   = w;              // 128
  float* w1t  = w + 128;        // 12288
  float* X1   = w + 12416;      // 131072
  float* f0   = w + 143488;     // 327680 (5 planes x 65536)
  float* f1   = w + 471168;     // 327680

  prep_kernel<<<2, 64, 0, stream>>>(Wq, bq, Wk, bk, Wv, bv, Wo, bw,
                                    W1, b1, W2, sm, w1t);
  feat_kernel<<<64, 256, 0, stream>>>(KEY, VALUE, sm, f0);

  // layer 0: queries/residual from KEY/VALUE, keys from f0; writes X1 + f1 (layer-1 sm)
  layer_kernel<<<512, 512, 0, stream>>>(KEY, VALUE, X1, f0,
      w1t, sm + 64,
      bo, g1, be1, b2, g2, be2,
      X1, f1, Wfc, bfc, out, 1, 0);

  // layer 1: consumes X1/f1, produces final output
  layer_kernel<<<512, 512, 0, stream>>>(KEY, VALUE, X1, f1,
      w1t + FF*12, sm,
      bo + 4, g1 + 4, be1 + 4, b2 + 4, g2 + 4, be2 + 4,
      X1, f1, Wfc, bfc, out, 0, 1);
}